// Round 3
// baseline (631.444 us; speedup 1.0000x reference)
//
#include <hip/hip_runtime.h>
#include <hip/hip_bf16.h>
#include <math.h>

using bf16 = __hip_bfloat16;
typedef __attribute__((ext_vector_type(8))) short s16x8;
typedef __attribute__((ext_vector_type(4))) float f32x4;

__device__ __forceinline__ float bf2f(unsigned short u) {
    return __uint_as_float(((unsigned int)u) << 16);
}
__device__ __forceinline__ unsigned short f2bf(float f) {
    union { bf16 b; unsigned short u; } cv; cv.b = __float2bfloat16(f); return cv.u;
}
__device__ __forceinline__ float4 ld4(const float* p) { return *(const float4*)p; }
__device__ __forceinline__ float4 ld4(const bf16* p) {
    ushort4 u = *(const ushort4*)p;
    return make_float4(bf2f(u.x), bf2f(u.y), bf2f(u.z), bf2f(u.w));
}

// tanh-form gelu, algebraically reduced:
//   gelu(v) = v - v * rcp(exp(v*(1.5957691 + 0.0713548*v^2)) + 1)
// ~8 VALU insts. max |err| ~3e-4 — far below bf16 storage noise.
__device__ __forceinline__ float gelu_f(float v) {
    const float t = v * v;
    const float z = v * fmaf(t, 0.07135481283f, 1.5957691216f);
    const float e = __expf(z);                       // +inf ok: r->0 -> v
    const float r = __builtin_amdgcn_rcpf(e + 1.f);  // e->0:  r->1 -> 0
    return fmaf(-v, r, v);
}

#define GLD16(g, l) __builtin_amdgcn_global_load_lds( \
    (const __attribute__((address_space(1))) unsigned int*)(const void*)(g), \
    (__attribute__((address_space(3))) unsigned int*)(void*)(l), 16, 0, 0)

// ---------------------------------------------------------------------------
// merged prep (index-range segmented).
// qkvT[896][384]: rows 0..95 = q_w^T, 96..127 = 0, 128..895 = kv_w^T.
// ---------------------------------------------------------------------------
__device__ __forceinline__ void wtbT(const float* __restrict__ src,
                                     bf16* __restrict__ dst, int K, int N, int i)
{
    int n = i / K, k = i % K;
    dst[i] = (n < N) ? __float2bfloat16(src[k * N + n]) : __float2bfloat16(0.f);
}

__global__ __launch_bounds__(256) void prep_kernel(
    const float* q_w, const float* kv_w, const float* proj_w,
    const float* w1, const float* w2,
    const float* cpe0_w, const float* cpe1_w,
    bf16* qkvT, bf16* pwT, bf16* w1T, bf16* w2T,
    float* wt0, float* wt1)
{
    int i = blockIdx.x * 256 + threadIdx.x;
    if (i < 344064) {                                   // [896][384]
        int n = i / 384, k = i % 384;
        float v = 0.f;
        if (n < 96)       v = q_w[k * 96 + n];
        else if (n >= 128) v = kv_w[k * 768 + (n - 128)];
        qkvT[i] = __float2bfloat16(v);
    }
    else if (i < 491520)  wtbT(proj_w, pwT,  384, 384,  i - 344064);
    else if (i < 1081344) wtbT(w1,     w1T,  384, 1536, i - 491520);
    else if (i < 1671168) wtbT(w2,     w2T,  1536, 384, i - 1081344);
    else if (i < 1681536) { int j = i - 1671168; wt0[(j % 27) * 384 + j / 27] = cpe0_w[j]; }
    else if (i < 1691904) { int j = i - 1681536; wt1[(j % 27) * 384 + j / 27] = cpe1_w[j]; }
}

// ---------------------------------------------------------------------------
// Depthwise 3x3x3 conv + bias + residual + FUSED LayerNorm.
// Block = one (b,d,h) row: 32 tokens x 384 ch. src fp32 or bf16 (templated);
// xf_out bf16 (pre-LN residual), t_out bf16 (LN result).
// ---------------------------------------------------------------------------
template <typename T>
__global__ __launch_bounds__(384) void cpe_ln_kernel(
    const T* __restrict__ src, const float* __restrict__ wgtT,
    const float* __restrict__ bias, const float* __restrict__ gam,
    const float* __restrict__ bet, bf16* __restrict__ xf_out,
    bf16* __restrict__ t_out)
{
    const int tid = threadIdx.x;
    const int qd = tid % 96, c = qd * 4;
    const int wseg = tid / 96, w_base = wseg * 8;
    const int blk = blockIdx.x;
    const int h = blk & 31, d = (blk >> 5) & 7, b = blk >> 8;

    const float4 bv = *(const float4*)(bias + c);
    float4 acc[8];
    #pragma unroll
    for (int o = 0; o < 8; ++o) acc[o] = bv;

    #pragma unroll
    for (int kd = 0; kd < 3; ++kd) {
        const int dd = d + kd - 1;
        if ((unsigned)dd >= 8u) continue;
        #pragma unroll
        for (int kh = 0; kh < 3; ++kh) {
            const int hh = h + kh - 1;
            if ((unsigned)hh >= 32u) continue;
            const int tap0 = kd * 9 + kh * 3;
            const float4 w0 = *(const float4*)(wgtT + (tap0 + 0) * 384 + c);
            const float4 w1 = *(const float4*)(wgtT + (tap0 + 1) * 384 + c);
            const float4 w2 = *(const float4*)(wgtT + (tap0 + 2) * 384 + c);
            const T* rowp = src + ((((size_t)b * 8 + dd) * 32 + hh) * 32) * 384 + c;
            #pragma unroll
            for (int p = 0; p < 10; ++p) {
                const int ww = w_base + p - 1;
                const float m = ((unsigned)ww < 32u) ? 1.f : 0.f;
                const int wwc = min(max(ww, 0), 31);
                float4 sv = ld4(rowp + (size_t)wwc * 384);
                sv.x *= m; sv.y *= m; sv.z *= m; sv.w *= m;
                if (p < 8) {
                    acc[p].x += sv.x * w0.x; acc[p].y += sv.y * w0.y;
                    acc[p].z += sv.z * w0.z; acc[p].w += sv.w * w0.w;
                }
                if (p >= 1 && p <= 8) {
                    acc[p-1].x += sv.x * w1.x; acc[p-1].y += sv.y * w1.y;
                    acc[p-1].z += sv.z * w1.z; acc[p-1].w += sv.w * w1.w;
                }
                if (p >= 2) {
                    acc[p-2].x += sv.x * w2.x; acc[p-2].y += sv.y * w2.y;
                    acc[p-2].z += sv.z * w2.z; acc[p-2].w += sv.w * w2.w;
                }
            }
        }
    }
    const size_t rowoff = ((((size_t)b * 8 + d) * 32 + h) * 32) * 384 + c;
    float4 r[8];
    __shared__ float2 part[32][96];
    #pragma unroll
    for (int o = 0; o < 8; ++o) {
        const size_t off = rowoff + (size_t)(w_base + o) * 384;
        const float4 s0 = ld4(src + off);
        r[o].x = s0.x + acc[o].x; r[o].y = s0.y + acc[o].y;
        r[o].z = s0.z + acc[o].z; r[o].w = s0.w + acc[o].w;
        ushort4 u;
        u.x = f2bf(r[o].x); u.y = f2bf(r[o].y); u.z = f2bf(r[o].z); u.w = f2bf(r[o].w);
        *(ushort4*)((unsigned short*)xf_out + off) = u;
        const float s = r[o].x + r[o].y + r[o].z + r[o].w;
        const float s2 = r[o].x*r[o].x + r[o].y*r[o].y + r[o].z*r[o].z + r[o].w*r[o].w;
        part[w_base + o][qd] = make_float2(s, s2);
    }
    __syncthreads();
    __shared__ float2 red[32][12];
    {
        const int tk = tid / 12, j = tid % 12;
        float s = 0.f, s2 = 0.f;
        #pragma unroll
        for (int u = 0; u < 8; ++u) {
            const float2 p = part[tk][j * 8 + u];
            s += p.x; s2 += p.y;
        }
        red[tk][j] = make_float2(s, s2);
    }
    __syncthreads();
    __shared__ float2 stats[32];
    if (tid < 32) {
        float s = 0.f, s2 = 0.f;
        #pragma unroll
        for (int j = 0; j < 12; ++j) { s += red[tid][j].x; s2 += red[tid][j].y; }
        const float mean = s * (1.f / 384.f);
        const float var = s2 * (1.f / 384.f) - mean * mean;
        stats[tid] = make_float2(mean, rsqrtf(var + 1e-5f));
    }
    __syncthreads();
    const float4 gv = *(const float4*)(gam + c);
    const float4 be = *(const float4*)(bet + c);
    #pragma unroll
    for (int o = 0; o < 8; ++o) {
        const int tk = w_base + o;
        const float2 st = stats[tk];
        ushort4 u;
        u.x = f2bf((r[o].x - st.x) * st.y * gv.x + be.x);
        u.y = f2bf((r[o].y - st.x) * st.y * gv.y + be.y);
        u.z = f2bf((r[o].z - st.x) * st.y * gv.z + be.z);
        u.w = f2bf((r[o].w - st.x) * st.y * gv.w + be.w);
        *(ushort4*)((unsigned short*)t_out + (size_t)(blk * 32 + tk) * 384 + c) = u;
    }
}

// ---------------------------------------------------------------------------
// GEMM: out[M,N] = A[M,K](bf16) @ BT[N,K]^T(bf16).  128x128 tile, BK=64.
// A staged via global_load_lds (XOR-swizzled, conflict-free).
// B NOT staged: fragments read directly from global — all B panels are
// L2-resident (<1.2 MB), and re-staging B through LDS was ~half of the
// staged-byte volume that bounds these kernels (~10 B/cyc/CU ceiling).
// Epilogue: LDS-transpose (reusing the 32KB LDS) for coalesced stores and
// vectorized residual loads.
// flags: 1 = gelu, 2 = out fp32 (else bf16), 4 = res bf16 (else fp32).
// All grids are exact multiples of 128 in both dims (no bounds checks).
// ---------------------------------------------------------------------------
__global__ __launch_bounds__(256) void gemm128_kernel(
    const bf16* __restrict__ A, int lda,
    const bf16* __restrict__ BT, int ldb,
    void* outp, int ldo, const void* resp, const float* __restrict__ bias,
    int Nout, int K, int flags)
{
    __shared__ unsigned short smem[2 * 128 * 64];   // loop uses 16KB (As); epilogue uses all
    unsigned short* As = smem;
    const int tid = threadIdx.x;
    const int wid = tid >> 6, lane = tid & 63;
    const int m0 = blockIdx.x * 128, n0 = blockIdx.y * 128;
    const int moff = (wid >> 1) * 64, noff = (wid & 1) * 64;
    const int lrow = lane & 15, quad = lane >> 4;
    const int srow = lane >> 3;
    const int scol = ((lane & 7) ^ srow) * 8;
    const int sw = lrow & 7;

    // direct-from-L2 B row pointers: row n0+noff+ni*16+lrow, k-base quad*8.
    // k-mapping identical to the retired LDS path: col = k0 + ks + quad*8.
    const bf16* Brow0 = BT + (size_t)(n0 + noff + lrow) * ldb + quad * 8;

    f32x4 acc[4][4] = {};

    for (int k0 = 0; k0 < K; k0 += 64) {
        #pragma unroll
        for (int j = 0; j < 4; ++j) {
            const int r = (wid * 4 + j) * 8 + srow;
            GLD16(A + (size_t)(m0 + r) * lda + k0 + scol, As + (wid * 4 + j) * 512);
        }
        __syncthreads();
        #pragma unroll
        for (int ks = 0; ks < 64; ks += 32) {
            const int kc = (ks >> 3) + quad;
            const int koff = ((kc ^ sw) << 3);
            s16x8 af[4], bfr[4];
            #pragma unroll
            for (int i = 0; i < 4; ++i)
                af[i] = *(const s16x8*)(As + (moff + i * 16 + lrow) * 64 + koff);
            #pragma unroll
            for (int i = 0; i < 4; ++i)
                bfr[i] = *(const s16x8*)(Brow0 + (size_t)i * 16 * ldb + k0 + ks);
            #pragma unroll
            for (int mi = 0; mi < 4; ++mi)
                #pragma unroll
                for (int ni = 0; ni < 4; ++ni)
                    acc[mi][ni] = __builtin_amdgcn_mfma_f32_16x16x32_bf16(
                        af[mi], bfr[ni], acc[mi][ni], 0, 0, 0);
        }
        __syncthreads();
    }

    const bool gelu  = (flags & 1) != 0;
    const bool ofp32 = (flags & 2) != 0;
    const bool rbf16 = (flags & 4) != 0;
    const int rbase = quad * 4;

    if (!ofp32 && !resp) {
        // --- Path 1: bf16 out, no residual (qkv, MLP1). Single pass. ---
        #pragma unroll
        for (int mi = 0; mi < 4; ++mi) {
            #pragma unroll
            for (int ni = 0; ni < 4; ++ni) {
                const int gn = n0 + noff + ni * 16 + lrow;
                const float bval = bias ? bias[gn] : 0.f;
                const int lc2 = (noff + ni * 16 + lrow) * 2;
                #pragma unroll
                for (int r = 0; r < 4; ++r) {
                    const int lr = moff + mi * 16 + rbase + r;
                    float v = acc[mi][ni][r] + bval;
                    if (gelu) v = gelu_f(v);
                    const int byte = lr * 256 + (lc2 ^ (((lr >> 2) & 3) << 5));
                    *(unsigned short*)((char*)smem + byte) = f2bf(v);
                }
            }
        }
        __syncthreads();
        #pragma unroll
        for (int it = 0; it < 8; ++it) {
            const int slot = tid + it * 256;           // 2048 slots of 16B
            const int row = slot >> 4, grp = slot & 15;
            const int byte = row * 256 + ((grp * 16) ^ (((row >> 2) & 3) << 5));
            const uint4 val = *(const uint4*)((const char*)smem + byte);
            *(uint4*)((unsigned short*)outp + (size_t)(m0 + row) * ldo + n0 + grp * 8) = val;
        }
    } else {
        // --- Path 2: residual and/or fp32 out (proj, MLP2). Two 64-col
        // passes of fp32 through LDS; residual added vectorized at readback.
        float* fs = (float*)smem;                      // [128][64] swizzled
        #pragma unroll
        for (int half = 0; half < 2; ++half) {
            if ((wid & 1) == half) {
                #pragma unroll
                for (int mi = 0; mi < 4; ++mi) {
                    #pragma unroll
                    for (int ni = 0; ni < 4; ++ni) {
                        const int gn = n0 + noff + ni * 16 + lrow;
                        const float bval = bias ? bias[gn] : 0.f;
                        const int lcl = ni * 16 + lrow;
                        #pragma unroll
                        for (int r = 0; r < 4; ++r) {
                            const int lr = moff + mi * 16 + rbase + r;
                            float v = acc[mi][ni][r] + bval;
                            if (gelu) v = gelu_f(v);
                            fs[lr * 64 + (lcl ^ (((lr >> 2) & 3) << 4))] = v;
                        }
                    }
                }
            }
            __syncthreads();
            #pragma unroll
            for (int it = 0; it < 8; ++it) {
                const int slot = tid + it * 256;       // 2048 slots of 4 cols
                const int row = slot >> 4, grp = slot & 15;
                const int word = row * 64 + ((grp * 4) ^ (((row >> 2) & 3) << 4));
                float4 v = *(const float4*)(fs + word);
                const size_t obase = (size_t)(m0 + row) * ldo + n0 + half * 64 + grp * 4;
                if (resp) {
                    if (rbf16) {
                        ushort4 u = *(const ushort4*)((const unsigned short*)resp + obase);
                        v.x += bf2f(u.x); v.y += bf2f(u.y);
                        v.z += bf2f(u.z); v.w += bf2f(u.w);
                    } else {
                        float4 rr = *(const float4*)((const float*)resp + obase);
                        v.x += rr.x; v.y += rr.y; v.z += rr.z; v.w += rr.w;
                    }
                }
                if (ofp32) {
                    *(float4*)((float*)outp + obase) = v;
                } else {
                    ushort4 u;
                    u.x = f2bf(v.x); u.y = f2bf(v.y); u.z = f2bf(v.z); u.w = f2bf(v.w);
                    *(ushort4*)((unsigned short*)outp + obase) = u;
                }
            }
            __syncthreads();
        }
    }
}

// ---------------------------------------------------------------------------
// Attention scores via MFMA: partial[c,d] = sum_{n in split} K[n,c]*V[n,d].
// qkv layout: row token, 896 cols: k at 128+g*192+h*48, v at 512+g*192+h*48.
// grid (32 bgh, 32 splits), block 64 (1 wave).
// ---------------------------------------------------------------------------
__global__ __launch_bounds__(64) void attp_kernel(
    const bf16* __restrict__ qkv, float* __restrict__ attp)
{
    const int bgh = blockIdx.x, split = blockIdx.y;
    const int b = bgh >> 3, rr = bgh & 7, g = rr >> 2, h = rr & 3;
    const int kcol = 128 + g * 192 + h * 48, vcol = 512 + g * 192 + h * 48;
    __shared__ unsigned short Ks[256 * 48];
    __shared__ unsigned short Vs[256 * 48];
    const int lane = threadIdx.x;

    const size_t rowbase = (size_t)(b * 8192 + split * 256) * 896;
    for (int i = lane; i < 256 * 6; i += 64) {
        const int row = i / 6, part = i % 6;
        const size_t gi = rowbase + (size_t)row * 896;
        *(uint4*)(Ks + row * 48 + part * 8) = *(const uint4*)(qkv + gi + kcol + part * 8);
        *(uint4*)(Vs + row * 48 + part * 8) = *(const uint4*)(qkv + gi + vcol + part * 8);
    }
    __syncthreads();

    f32x4 acc[3][3] = {};
    const int col = lane & 15, kb = (lane >> 4) * 8;
    for (int ks = 0; ks < 256; ks += 32) {
        s16x8 af[3], bfr[3];
        #pragma unroll
        for (int t3 = 0; t3 < 3; ++t3) {
            #pragma unroll
            for (int j = 0; j < 8; ++j) {
                const int tok = ks + kb + j;
                af[t3][j]  = (short)Ks[tok * 48 + t3 * 16 + col];
                bfr[t3][j] = (short)Vs[tok * 48 + t3 * 16 + col];
            }
        }
        #pragma unroll
        for (int ct = 0; ct < 3; ++ct)
            #pragma unroll
            for (int dt = 0; dt < 3; ++dt)
                acc[ct][dt] = __builtin_amdgcn_mfma_f32_16x16x32_bf16(
                    af[ct], bfr[dt], acc[ct][dt], 0, 0, 0);
    }
    const float scale = 0.14433756729740643f;  // 48^-0.5
    float* op = attp + ((size_t)bgh * 32 + split) * 2304;
    const int rbase = (lane >> 4) * 4;
    #pragma unroll
    for (int ct = 0; ct < 3; ++ct)
        #pragma unroll
        for (int dt = 0; dt < 3; ++dt)
            #pragma unroll
            for (int r = 0; r < 4; ++r)
                op[(ct * 16 + rbase + r) * 48 + dt * 16 + col] = scale * acc[ct][dt][r];
}

// ---------------------------------------------------------------------------
// reduce 32 splits + fp32 row-softmax, cast to bf16.
// grid (48 rows, 32 bgh), block 64 (1 wave).
// ---------------------------------------------------------------------------
__global__ __launch_bounds__(64) void attred_kernel(
    const float* __restrict__ attp, bf16* __restrict__ att)
{
    const int c = blockIdx.x, bgh = blockIdx.y, lane = threadIdx.x;
    const float* base = attp + (size_t)bgh * 32 * 2304 + c * 48;
    float s = 0.f;
    if (lane < 48) {
        #pragma unroll
        for (int sp = 0; sp < 32; ++sp) s += base[(size_t)sp * 2304 + lane];
    }
    float m = (lane < 48) ? s : -3.0e38f;
    #pragma unroll
    for (int off = 32; off >= 1; off >>= 1) m = fmaxf(m, __shfl_xor(m, off));
    const float e = (lane < 48) ? __expf(s - m) : 0.f;
    float t = e;
    #pragma unroll
    for (int off = 32; off >= 1; off >>= 1) t += __shfl_xor(t, off);
    if (lane < 48)
        att[(size_t)bgh * 2304 + c * 48 + lane] =
            __float2bfloat16(e * __builtin_amdgcn_rcpf(t));
}

// ---------------------------------------------------------------------------
// y = Q_g(8192x48) @ att^T(48x48) per (b,h2g), MFMA, K=48 padded to 64.
// Q read from merged qkv (ld 896, cols g*48..). Scrambled write.
// ---------------------------------------------------------------------------
__global__ __launch_bounds__(256) void y_kernel(
    const bf16* __restrict__ qkv, const bf16* __restrict__ att, bf16* __restrict__ y)
{
    const int m0 = blockIdx.x * 128;
    const int b = blockIdx.y >> 3, h2g = blockIdx.y & 7;
    const int g = h2g & 1, hh = h2g >> 1;
    const int bgh = b * 8 + g * 4 + hh;
    const int tid = threadIdx.x, wid = tid >> 6, lane = tid & 63;
    __shared__ unsigned short Qs[128 * 64];
    __shared__ unsigned short Ats[48 * 64];

    for (int i = tid; i < 128 * 6; i += 256) {
        const int row = i / 6, part = i % 6;
        *(uint4*)(Qs + row * 64 + part * 8) =
            *(const uint4*)(qkv + (size_t)(b * 8192 + m0 + row) * 896 + g * 48 + part * 8);
    }
    {
        const int row = tid / 2, half = tid & 1;
        *(uint4*)(Qs + row * 64 + 48 + half * 8) = make_uint4(0, 0, 0, 0);
    }
    for (int i = tid; i < 48 * 6; i += 256) {
        const int row = i / 6, part = i % 6;
        *(uint4*)(Ats + row * 64 + part * 8) =
            *(const uint4*)(att + (size_t)bgh * 2304 + row * 48 + part * 8);
    }
    for (int i = tid; i < 96; i += 256) {
        const int row = i / 2, half = i & 1;
        *(uint4*)(Ats + row * 64 + 48 + half * 8) = make_uint4(0, 0, 0, 0);
    }
    __syncthreads();

    const int moff = wid * 32;
    const int col = lane & 15, kb = (lane >> 4) * 8;
    f32x4 acc[2][3] = {};
    #pragma unroll
    for (int ks = 0; ks < 64; ks += 32) {
        s16x8 af[2], bfr[3];
        #pragma unroll
        for (int mt = 0; mt < 2; ++mt)
            af[mt] = *(const s16x8*)(Qs + (moff + mt * 16 + col) * 64 + ks + kb);
        #pragma unroll
        for (int nt = 0; nt < 3; ++nt)
            bfr[nt] = *(const s16x8*)(Ats + (nt * 16 + col) * 64 + ks + kb);
        #pragma unroll
        for (int mt = 0; mt < 2; ++mt)
            #pragma unroll
            for (int nt = 0; nt < 3; ++nt)
                acc[mt][nt] = __builtin_amdgcn_mfma_f32_16x16x32_bf16(
                    af[mt], bfr[nt], acc[mt][nt], 0, 0, 0);
    }
    const int rbase = (lane >> 4) * 4;
    #pragma unroll
    for (int mt = 0; mt < 2; ++mt) {
        #pragma unroll
        for (int nt = 0; nt < 3; ++nt) {
            const int d = nt * 16 + col;
            #pragma unroll
            for (int r = 0; r < 4; ++r) {
                const int n = m0 + moff + mt * 16 + rbase + r;
                y[((size_t)b * 8192 + h2g * 1024 + (n >> 3)) * 384 + (n & 7) * 48 + d] =
                    __float2bfloat16(acc[mt][nt][r]);
            }
        }
    }
}

// ---------------------------------------------------------------------------
extern "C" void kernel_launch(void* const* d_in, const int* in_sizes, int n_in,
                              void* d_out, int out_size, void* d_ws, size_t ws_size,
                              hipStream_t stream)
{
    (void)in_sizes; (void)n_in; (void)out_size; (void)ws_size;
    const float* x      = (const float*)d_in[0];
    const float* cpe0_w = (const float*)d_in[2];
    const float* cpe0_b = (const float*)d_in[3];
    const float* cpe1_w = (const float*)d_in[4];
    const float* cpe1_b = (const float*)d_in[5];
    const float* n1g    = (const float*)d_in[6];
    const float* n1b    = (const float*)d_in[7];
    const float* q_w    = (const float*)d_in[8];
    const float* kv_w   = (const float*)d_in[9];
    const float* proj_w = (const float*)d_in[10];
    const float* proj_b = (const float*)d_in[11];
    const float* n2g    = (const float*)d_in[12];
    const float* n2b    = (const float*)d_in[13];
    const float* w1     = (const float*)d_in[14];
    const float* b1     = (const float*)d_in[15];
    const float* w2     = (const float*)d_in[16];
    const float* b2     = (const float*)d_in[17];

    char* ws = (char*)d_ws;
    // persistent weights: 0 .. 3.3 MiB
    bf16*  qkvT = (bf16*)(ws + 0);           // [896][384]
    bf16*  pwT  = (bf16*)(ws + 688128);      // [384][384]
    bf16*  w1T  = (bf16*)(ws + 983040);      // [1536][384]
    bf16*  w2T  = (bf16*)(ws + 2162688);     // [384][1536]
    float* wt0  = (float*)(ws + 3342336);
    float* wt1  = (float*)(ws + 3383808);
    // dynamic buffers
    bf16*  xf   = (bf16*)(ws + 4194304);     // 24 MiB residual1
    bf16*  qkv  = (bf16*)(ws + 29360128);    // 56 MiB [32768][896]
    float* attp = (float*)(ws + 88080384);   //  9 MiB
    bf16*  att  = (bf16*)(ws + 97517568);    //  144 KiB
    bf16*  yb   = (bf16*)(ws + 98566144);    // 24 MiB
    bf16*  t    = (bf16*)(ws + 123731968);   // 24 MiB LN out
    bf16*  xf3  = (bf16*)(ws + 148897792);   // 24 MiB residual2
    bf16*  h1   = (bf16*)(ws + 4194304);     // 96 MiB (phase-2; aliases xf..yb, all dead)

    // 0. merged prep
    prep_kernel<<<dim3(6609), dim3(256), 0, stream>>>(
        q_w, kv_w, proj_w, w1, w2, cpe0_w, cpe1_w,
        qkvT, pwT, w1T, w2T, wt0, wt1);

    // 1. CPE0 + LN1: xf(bf16) = x + dwconv(x) + b ; t = LN(xf)
    cpe_ln_kernel<float><<<dim3(1024), dim3(384), 0, stream>>>(
        x, wt0, cpe0_b, n1g, n1b, xf, t);
    // 2. merged q+kv projection: qkv = t @ qkvT^T   (grid m-major for XCD locality)
    gemm128_kernel<<<dim3(256, 7), dim3(256), 0, stream>>>(
        t, 384, qkvT, 384, qkv, 896, nullptr, nullptr, 896, 384, 0);
    // 3/4. channel-attention scores + softmax
    attp_kernel<<<dim3(32, 32), dim3(64), 0, stream>>>(qkv, attp);
    attred_kernel<<<dim3(48, 32), dim3(64), 0, stream>>>(attp, att);
    // 5. y = q @ att^T with scrambled reshape
    y_kernel<<<dim3(64, 32), dim3(256), 0, stream>>>(qkv, att, yb);
    // 6. proj (in-place bf16 residual): xf = yb @ pw + pb + xf
    gemm128_kernel<<<dim3(256, 3), dim3(256), 0, stream>>>(
        yb, 384, pwT, 384, xf, 384, xf, proj_b, 384, 384, 4);
    // 7. CPE1 + LN2: xf3(bf16) = xf + dwconv(xf) + b ; t = LN(xf3)
    cpe_ln_kernel<bf16><<<dim3(1024), dim3(384), 0, stream>>>(
        xf, wt1, cpe1_b, n2g, n2b, xf3, t);
    // 8. MLP: h1 = gelu(t@W1+b1); out = h1@W2 + b2 + xf3 (fp32)
    gemm128_kernel<<<dim3(256, 12), dim3(256), 0, stream>>>(
        t, 384, w1T, 384, h1, 1536, nullptr, b1, 1536, 384, 1);
    gemm128_kernel<<<dim3(256, 3), dim3(256), 0, stream>>>(
        h1, 1536, w2T, 1536, d_out, 384, xf3, b2, 384, 1536, 2 | 4);
}

// Round 5
// 455.289 us; speedup vs baseline: 1.3869x; 1.3869x over previous
//
#include <hip/hip_runtime.h>
#include <hip/hip_bf16.h>
#include <math.h>

using bf16 = __hip_bfloat16;
typedef __attribute__((ext_vector_type(8))) short s16x8;
typedef __attribute__((ext_vector_type(4))) float f32x4;

__device__ __forceinline__ float bf2f(unsigned short u) {
    return __uint_as_float(((unsigned int)u) << 16);
}
__device__ __forceinline__ unsigned short f2bf(float f) {
    union { bf16 b; unsigned short u; } cv; cv.b = __float2bfloat16(f); return cv.u;
}
__device__ __forceinline__ float4 ld4(const float* p) { return *(const float4*)p; }
__device__ __forceinline__ float4 ld4(const bf16* p) {
    ushort4 u = *(const ushort4*)p;
    return make_float4(bf2f(u.x), bf2f(u.y), bf2f(u.z), bf2f(u.w));
}

// tanh-form gelu, algebraically reduced:
//   gelu(v) = v - v * rcp(exp(v*(1.5957691 + 0.0713548*v^2)) + 1)
// ~8 VALU insts. max |err| ~3e-4 — far below bf16 storage noise.
__device__ __forceinline__ float gelu_f(float v) {
    const float t = v * v;
    const float z = v * fmaf(t, 0.07135481283f, 1.5957691216f);
    const float e = __expf(z);                       // +inf ok: r->0 -> v
    const float r = __builtin_amdgcn_rcpf(e + 1.f);  // e->0:  r->1 -> 0
    return fmaf(-v, r, v);
}

#define GLD16(g, l) __builtin_amdgcn_global_load_lds( \
    (const __attribute__((address_space(1))) unsigned int*)(const void*)(g), \
    (__attribute__((address_space(3))) unsigned int*)(void*)(l), 16, 0, 0)

// ---------------------------------------------------------------------------
// merged prep (index-range segmented).
// qkvT[896][384]: rows 0..95 = q_w^T, 96..127 = 0, 128..895 = kv_w^T.
// ---------------------------------------------------------------------------
__device__ __forceinline__ void wtbT(const float* __restrict__ src,
                                     bf16* __restrict__ dst, int K, int N, int i)
{
    int n = i / K, k = i % K;
    dst[i] = (n < N) ? __float2bfloat16(src[k * N + n]) : __float2bfloat16(0.f);
}

__global__ __launch_bounds__(256) void prep_kernel(
    const float* q_w, const float* kv_w, const float* proj_w,
    const float* w1, const float* w2,
    const float* cpe0_w, const float* cpe1_w,
    bf16* qkvT, bf16* pwT, bf16* w1T, bf16* w2T,
    float* wt0, float* wt1)
{
    int i = blockIdx.x * 256 + threadIdx.x;
    if (i < 344064) {                                   // [896][384]
        int n = i / 384, k = i % 384;
        float v = 0.f;
        if (n < 96)       v = q_w[k * 96 + n];
        else if (n >= 128) v = kv_w[k * 768 + (n - 128)];
        qkvT[i] = __float2bfloat16(v);
    }
    else if (i < 491520)  wtbT(proj_w, pwT,  384, 384,  i - 344064);
    else if (i < 1081344) wtbT(w1,     w1T,  384, 1536, i - 491520);
    else if (i < 1671168) wtbT(w2,     w2T,  1536, 384, i - 1081344);
    else if (i < 1681536) { int j = i - 1671168; wt0[(j % 27) * 384 + j / 27] = cpe0_w[j]; }
    else if (i < 1691904) { int j = i - 1681536; wt1[(j % 27) * 384 + j / 27] = cpe1_w[j]; }
}

// ---------------------------------------------------------------------------
// Depthwise 3x3x3 conv + bias + residual + FUSED LayerNorm.
// Block = one (b,d,h) row: 32 tokens x 384 ch. src fp32 or bf16 (templated);
// xf_out bf16 (pre-LN residual), t_out bf16 (LN result).
// ---------------------------------------------------------------------------
template <typename T>
__global__ __launch_bounds__(384) void cpe_ln_kernel(
    const T* __restrict__ src, const float* __restrict__ wgtT,
    const float* __restrict__ bias, const float* __restrict__ gam,
    const float* __restrict__ bet, bf16* __restrict__ xf_out,
    bf16* __restrict__ t_out)
{
    const int tid = threadIdx.x;
    const int qd = tid % 96, c = qd * 4;
    const int wseg = tid / 96, w_base = wseg * 8;
    const int blk = blockIdx.x;
    const int h = blk & 31, d = (blk >> 5) & 7, b = blk >> 8;

    const float4 bv = *(const float4*)(bias + c);
    float4 acc[8];
    #pragma unroll
    for (int o = 0; o < 8; ++o) acc[o] = bv;

    #pragma unroll
    for (int kd = 0; kd < 3; ++kd) {
        const int dd = d + kd - 1;
        if ((unsigned)dd >= 8u) continue;
        #pragma unroll
        for (int kh = 0; kh < 3; ++kh) {
            const int hh = h + kh - 1;
            if ((unsigned)hh >= 32u) continue;
            const int tap0 = kd * 9 + kh * 3;
            const float4 w0 = *(const float4*)(wgtT + (tap0 + 0) * 384 + c);
            const float4 w1 = *(const float4*)(wgtT + (tap0 + 1) * 384 + c);
            const float4 w2 = *(const float4*)(wgtT + (tap0 + 2) * 384 + c);
            const T* rowp = src + ((((size_t)b * 8 + dd) * 32 + hh) * 32) * 384 + c;
            #pragma unroll
            for (int p = 0; p < 10; ++p) {
                const int ww = w_base + p - 1;
                const float m = ((unsigned)ww < 32u) ? 1.f : 0.f;
                const int wwc = min(max(ww, 0), 31);
                float4 sv = ld4(rowp + (size_t)wwc * 384);
                sv.x *= m; sv.y *= m; sv.z *= m; sv.w *= m;
                if (p < 8) {
                    acc[p].x += sv.x * w0.x; acc[p].y += sv.y * w0.y;
                    acc[p].z += sv.z * w0.z; acc[p].w += sv.w * w0.w;
                }
                if (p >= 1 && p <= 8) {
                    acc[p-1].x += sv.x * w1.x; acc[p-1].y += sv.y * w1.y;
                    acc[p-1].z += sv.z * w1.z; acc[p-1].w += sv.w * w1.w;
                }
                if (p >= 2) {
                    acc[p-2].x += sv.x * w2.x; acc[p-2].y += sv.y * w2.y;
                    acc[p-2].z += sv.z * w2.z; acc[p-2].w += sv.w * w2.w;
                }
            }
        }
    }
    const size_t rowoff = ((((size_t)b * 8 + d) * 32 + h) * 32) * 384 + c;
    float4 r[8];
    __shared__ float2 part[32][96];
    #pragma unroll
    for (int o = 0; o < 8; ++o) {
        const size_t off = rowoff + (size_t)(w_base + o) * 384;
        const float4 s0 = ld4(src + off);
        r[o].x = s0.x + acc[o].x; r[o].y = s0.y + acc[o].y;
        r[o].z = s0.z + acc[o].z; r[o].w = s0.w + acc[o].w;
        ushort4 u;
        u.x = f2bf(r[o].x); u.y = f2bf(r[o].y); u.z = f2bf(r[o].z); u.w = f2bf(r[o].w);
        *(ushort4*)((unsigned short*)xf_out + off) = u;
        const float s = r[o].x + r[o].y + r[o].z + r[o].w;
        const float s2 = r[o].x*r[o].x + r[o].y*r[o].y + r[o].z*r[o].z + r[o].w*r[o].w;
        part[w_base + o][qd] = make_float2(s, s2);
    }
    __syncthreads();
    __shared__ float2 red[32][12];
    {
        const int tk = tid / 12, j = tid % 12;
        float s = 0.f, s2 = 0.f;
        #pragma unroll
        for (int u = 0; u < 8; ++u) {
            const float2 p = part[tk][j * 8 + u];
            s += p.x; s2 += p.y;
        }
        red[tk][j] = make_float2(s, s2);
    }
    __syncthreads();
    __shared__ float2 stats[32];
    if (tid < 32) {
        float s = 0.f, s2 = 0.f;
        #pragma unroll
        for (int j = 0; j < 12; ++j) { s += red[tid][j].x; s2 += red[tid][j].y; }
        const float mean = s * (1.f / 384.f);
        const float var = s2 * (1.f / 384.f) - mean * mean;
        stats[tid] = make_float2(mean, rsqrtf(var + 1e-5f));
    }
    __syncthreads();
    const float4 gv = *(const float4*)(gam + c);
    const float4 be = *(const float4*)(bet + c);
    #pragma unroll
    for (int o = 0; o < 8; ++o) {
        const int tk = w_base + o;
        const float2 st = stats[tk];
        ushort4 u;
        u.x = f2bf((r[o].x - st.x) * st.y * gv.x + be.x);
        u.y = f2bf((r[o].y - st.x) * st.y * gv.y + be.y);
        u.z = f2bf((r[o].z - st.x) * st.y * gv.z + be.z);
        u.w = f2bf((r[o].w - st.x) * st.y * gv.w + be.w);
        *(ushort4*)((unsigned short*)t_out + (size_t)(blk * 32 + tk) * 384 + c) = u;
    }
}

// ---------------------------------------------------------------------------
// GEMM (R1-exact): out[M,N] = A[M,K](bf16) @ BT[N,K]^T(bf16). 128x128 tile,
// BK=64, global_load_lds w16, XOR-swizzled LDS (conflict-free).
// flags: 1 = gelu, 2 = out fp32 (else bf16), 4 = res bf16 (else fp32).
// Used for proj and MLP2 (residual paths).
// ---------------------------------------------------------------------------
__global__ __launch_bounds__(256) void gemm128_kernel(
    const bf16* __restrict__ A, int lda,
    const bf16* __restrict__ BT, int ldb,
    void* outp, int ldo, const void* resp, const float* __restrict__ bias,
    int Nout, int K, int flags)
{
    __shared__ unsigned short As[128 * 64];
    __shared__ unsigned short Bs[128 * 64];
    const int tid = threadIdx.x;
    const int wid = tid >> 6, lane = tid & 63;
    const int m0 = blockIdx.x * 128, n0 = blockIdx.y * 128;
    const int moff = (wid >> 1) * 64, noff = (wid & 1) * 64;
    const int lrow = lane & 15, quad = lane >> 4;
    const int srow = lane >> 3;
    const int scol = ((lane & 7) ^ srow) * 8;
    const int sw = lrow & 7;

    f32x4 acc[4][4] = {};

    for (int k0 = 0; k0 < K; k0 += 64) {
        #pragma unroll
        for (int j = 0; j < 4; ++j) {
            const int r = (wid * 4 + j) * 8 + srow;
            GLD16(A + (size_t)(m0 + r) * lda + k0 + scol, As + (wid * 4 + j) * 512);
        }
        #pragma unroll
        for (int j = 0; j < 4; ++j) {
            const int r = (wid * 4 + j) * 8 + srow;
            GLD16(BT + (size_t)(n0 + r) * ldb + k0 + scol, Bs + (wid * 4 + j) * 512);
        }
        __syncthreads();
        #pragma unroll
        for (int ks = 0; ks < 64; ks += 32) {
            const int kc = (ks >> 3) + quad;
            const int koff = ((kc ^ sw) << 3);
            s16x8 af[4], bfr[4];
            #pragma unroll
            for (int i = 0; i < 4; ++i)
                af[i] = *(const s16x8*)(As + (moff + i * 16 + lrow) * 64 + koff);
            #pragma unroll
            for (int i = 0; i < 4; ++i)
                bfr[i] = *(const s16x8*)(Bs + (noff + i * 16 + lrow) * 64 + koff);
            #pragma unroll
            for (int mi = 0; mi < 4; ++mi)
                #pragma unroll
                for (int ni = 0; ni < 4; ++ni)
                    acc[mi][ni] = __builtin_amdgcn_mfma_f32_16x16x32_bf16(
                        af[mi], bfr[ni], acc[mi][ni], 0, 0, 0);
        }
        __syncthreads();
    }

    const bool gelu  = (flags & 1) != 0;
    const bool ofp32 = (flags & 2) != 0;
    const bool rbf16 = (flags & 4) != 0;
    const int rbase = quad * 4;
    #pragma unroll
    for (int mi = 0; mi < 4; ++mi) {
        #pragma unroll
        for (int ni = 0; ni < 4; ++ni) {
            const int gn = n0 + noff + ni * 16 + lrow;
            if (gn >= Nout) continue;
            const float bval = bias ? bias[gn] : 0.f;
            #pragma unroll
            for (int r = 0; r < 4; ++r) {
                const int gm = m0 + moff + mi * 16 + rbase + r;
                const size_t oi = (size_t)gm * ldo + gn;
                float v = acc[mi][ni][r] + bval;
                if (gelu) v = gelu_f(v);
                if (resp) v += rbf16 ? bf2f(((const unsigned short*)resp)[oi])
                                     : ((const float*)resp)[oi];
                if (ofp32) ((float*)outp)[oi] = v;
                else       ((bf16*)outp)[oi] = __float2bfloat16(v);
            }
        }
    }
}

// ---------------------------------------------------------------------------
// GEMM 256x128 tile, BK=64, 512 threads (8 waves, 4m x 2n of 64x64 each).
// Same verified inner structure as gemm128 (XOR-swizzled LDS staging, MFMA
// 16x16x32). Halves per-output staged-byte volume vs 128x128 (B panel
// amortized over 2x rows). Epilogue: Path-1 LDS transpose (two 128-row
// passes through the 32KB As region) -> coalesced dwordx4 stores.
// bf16 out only, no residual. flags: 1 = gelu. M%256==0, N%128==0.
// ---------------------------------------------------------------------------
__global__ __launch_bounds__(512) void gemm256_kernel(
    const bf16* __restrict__ A, int lda,
    const bf16* __restrict__ BT, int ldb,
    bf16* __restrict__ outp, int ldo, const float* __restrict__ bias,
    int K, int flags)
{
    __shared__ unsigned short As[256 * 64];    // 32KB; epilogue transpose buffer
    __shared__ unsigned short Bs[128 * 64];    // 16KB
    const int tid = threadIdx.x;
    const int wid = tid >> 6, lane = tid & 63;
    const int m0 = blockIdx.x * 256, n0 = blockIdx.y * 128;
    const int moff = (wid >> 1) * 64, noff = (wid & 1) * 64;
    const int lrow = lane & 15, quad = lane >> 4;
    const int srow = lane >> 3;
    const int scol = ((lane & 7) ^ srow) * 8;
    const int sw = lrow & 7;

    f32x4 acc[4][4] = {};

    for (int k0 = 0; k0 < K; k0 += 64) {
        #pragma unroll
        for (int j = 0; j < 4; ++j) {
            const int r = (wid * 4 + j) * 8 + srow;        // rows 0..255
            GLD16(A + (size_t)(m0 + r) * lda + k0 + scol, As + (wid * 4 + j) * 512);
        }
        #pragma unroll
        for (int j = 0; j < 2; ++j) {
            const int r = (wid * 2 + j) * 8 + srow;        // rows 0..127
            GLD16(BT + (size_t)(n0 + r) * ldb + k0 + scol, Bs + (wid * 2 + j) * 512);
        }
        __syncthreads();
        #pragma unroll
        for (int ks = 0; ks < 64; ks += 32) {
            const int kc = (ks >> 3) + quad;
            const int koff = ((kc ^ sw) << 3);
            s16x8 af[4], bfr[4];
            #pragma unroll
            for (int i = 0; i < 4; ++i)
                af[i] = *(const s16x8*)(As + (moff + i * 16 + lrow) * 64 + koff);
            #pragma unroll
            for (int i = 0; i < 4; ++i)
                bfr[i] = *(const s16x8*)(Bs + (noff + i * 16 + lrow) * 64 + koff);
            #pragma unroll
            for (int mi = 0; mi < 4; ++mi)
                #pragma unroll
                for (int ni = 0; ni < 4; ++ni)
                    acc[mi][ni] = __builtin_amdgcn_mfma_f32_16x16x32_bf16(
                        af[mi], bfr[ni], acc[mi][ni], 0, 0, 0);
        }
        __syncthreads();
    }

    // Epilogue: two 128-row transpose passes (waves 0-3 own rows 0-127,
    // waves 4-7 own rows 128-255). Writer swizzle byte ^= ((lr>>2)&3)<<5:
    // 32 banks, 2 bf16/dword -> conflict-free (R2-verified, SQ_LDS_BANK_CONFLICT=0).
    const bool gelu = (flags & 1) != 0;
    const int rbase = quad * 4;
    #pragma unroll
    for (int pass = 0; pass < 2; ++pass) {
        if ((wid >> 2) == pass) {
            #pragma unroll
            for (int mi = 0; mi < 4; ++mi) {
                #pragma unroll
                for (int ni = 0; ni < 4; ++ni) {
                    const int gn = n0 + noff + ni * 16 + lrow;
                    const float bval = bias ? bias[gn] : 0.f;
                    const int lc2 = (noff + ni * 16 + lrow) * 2;
                    #pragma unroll
                    for (int r = 0; r < 4; ++r) {
                        const int lr = (moff & 127) + mi * 16 + rbase + r;  // 0..127
                        float v = acc[mi][ni][r] + bval;
                        if (gelu) v = gelu_f(v);
                        const int byte = lr * 256 + (lc2 ^ (((lr >> 2) & 3) << 5));
                        *(unsigned short*)((char*)As + byte) = f2bf(v);
                    }
                }
            }
        }
        __syncthreads();
        #pragma unroll
        for (int it = 0; it < 4; ++it) {
            const int slot = tid + it * 512;               // 2048 slots of 16B
            const int row = slot >> 4, grp = slot & 15;
            const int byte = row * 256 + ((grp * 16) ^ (((row >> 2) & 3) << 5));
            const uint4 val = *(const uint4*)((const char*)As + byte);
            *(uint4*)((unsigned short*)outp +
                      (size_t)(m0 + pass * 128 + row) * ldo + n0 + grp * 8) = val;
        }
        __syncthreads();
    }
}

// ---------------------------------------------------------------------------
// Attention scores via MFMA: partial[c,d] = sum_{n in split} K[n,c]*V[n,d].
// qkv layout: row token, 896 cols: k at 128+g*192+h*48, v at 512+g*192+h*48.
// grid (32 bgh, 32 splits), block 64 (1 wave).
// ---------------------------------------------------------------------------
__global__ __launch_bounds__(64) void attp_kernel(
    const bf16* __restrict__ qkv, float* __restrict__ attp)
{
    const int bgh = blockIdx.x, split = blockIdx.y;
    const int b = bgh >> 3, rr = bgh & 7, g = rr >> 2, h = rr & 3;
    const int kcol = 128 + g * 192 + h * 48, vcol = 512 + g * 192 + h * 48;
    __shared__ unsigned short Ks[256 * 48];
    __shared__ unsigned short Vs[256 * 48];
    const int lane = threadIdx.x;

    const size_t rowbase = (size_t)(b * 8192 + split * 256) * 896;
    for (int i = lane; i < 256 * 6; i += 64) {
        const int row = i / 6, part = i % 6;
        const size_t gi = rowbase + (size_t)row * 896;
        *(uint4*)(Ks + row * 48 + part * 8) = *(const uint4*)(qkv + gi + kcol + part * 8);
        *(uint4*)(Vs + row * 48 + part * 8) = *(const uint4*)(qkv + gi + vcol + part * 8);
    }
    __syncthreads();

    f32x4 acc[3][3] = {};
    const int col = lane & 15, kb = (lane >> 4) * 8;
    for (int ks = 0; ks < 256; ks += 32) {
        s16x8 af[3], bfr[3];
        #pragma unroll
        for (int t3 = 0; t3 < 3; ++t3) {
            #pragma unroll
            for (int j = 0; j < 8; ++j) {
                const int tok = ks + kb + j;
                af[t3][j]  = (short)Ks[tok * 48 + t3 * 16 + col];
                bfr[t3][j] = (short)Vs[tok * 48 + t3 * 16 + col];
            }
        }
        #pragma unroll
        for (int ct = 0; ct < 3; ++ct)
            #pragma unroll
            for (int dt = 0; dt < 3; ++dt)
                acc[ct][dt] = __builtin_amdgcn_mfma_f32_16x16x32_bf16(
                    af[ct], bfr[dt], acc[ct][dt], 0, 0, 0);
    }
    const float scale = 0.14433756729740643f;  // 48^-0.5
    float* op = attp + ((size_t)bgh * 32 + split) * 2304;
    const int rbase = (lane >> 4) * 4;
    #pragma unroll
    for (int ct = 0; ct < 3; ++ct)
        #pragma unroll
        for (int dt = 0; dt < 3; ++dt)
            #pragma unroll
            for (int r = 0; r < 4; ++r)
                op[(ct * 16 + rbase + r) * 48 + dt * 16 + col] = scale * acc[ct][dt][r];
}

// ---------------------------------------------------------------------------
// reduce 32 splits + fp32 row-softmax, cast to bf16.
// grid (48 rows, 32 bgh), block 64 (1 wave).
// ---------------------------------------------------------------------------
__global__ __launch_bounds__(64) void attred_kernel(
    const float* __restrict__ attp, bf16* __restrict__ att)
{
    const int c = blockIdx.x, bgh = blockIdx.y, lane = threadIdx.x;
    const float* base = attp + (size_t)bgh * 32 * 2304 + c * 48;
    float s = 0.f;
    if (lane < 48) {
        #pragma unroll
        for (int sp = 0; sp < 32; ++sp) s += base[(size_t)sp * 2304 + lane];
    }
    float m = (lane < 48) ? s : -3.0e38f;
    #pragma unroll
    for (int off = 32; off >= 1; off >>= 1) m = fmaxf(m, __shfl_xor(m, off));
    const float e = (lane < 48) ? __expf(s - m) : 0.f;
    float t = e;
    #pragma unroll
    for (int off = 32; off >= 1; off >>= 1) t += __shfl_xor(t, off);
    if (lane < 48)
        att[(size_t)bgh * 2304 + c * 48 + lane] =
            __float2bfloat16(e * __builtin_amdgcn_rcpf(t));
}

// ---------------------------------------------------------------------------
// y = Q_g(8192x48) @ att^T(48x48) per (b,h2g), MFMA, K=48 padded to 64.
// Q read from merged qkv (ld 896, cols g*48..). Scrambled write.
// ---------------------------------------------------------------------------
__global__ __launch_bounds__(256) void y_kernel(
    const bf16* __restrict__ qkv, const bf16* __restrict__ att, bf16* __restrict__ y)
{
    const int m0 = blockIdx.x * 128;
    const int b = blockIdx.y >> 3, h2g = blockIdx.y & 7;
    const int g = h2g & 1, hh = h2g >> 1;
    const int bgh = b * 8 + g * 4 + hh;
    const int tid = threadIdx.x, wid = tid >> 6, lane = tid & 63;
    __shared__ unsigned short Qs[128 * 64];
    __shared__ unsigned short Ats[48 * 64];

    for (int i = tid; i < 128 * 6; i += 256) {
        const int row = i / 6, part = i % 6;
        *(uint4*)(Qs + row * 64 + part * 8) =
            *(const uint4*)(qkv + (size_t)(b * 8192 + m0 + row) * 896 + g * 48 + part * 8);
    }
    {
        const int row = tid / 2, half = tid & 1;
        *(uint4*)(Qs + row * 64 + 48 + half * 8) = make_uint4(0, 0, 0, 0);
    }
    for (int i = tid; i < 48 * 6; i += 256) {
        const int row = i / 6, part = i % 6;
        *(uint4*)(Ats + row * 64 + part * 8) =
            *(const uint4*)(att + (size_t)bgh * 2304 + row * 48 + part * 8);
    }
    for (int i = tid; i < 96; i += 256) {
        const int row = i / 2, half = i & 1;
        *(uint4*)(Ats + row * 64 + 48 + half * 8) = make_uint4(0, 0, 0, 0);
    }
    __syncthreads();

    const int moff = wid * 32;
    const int col = lane & 15, kb = (lane >> 4) * 8;
    f32x4 acc[2][3] = {};
    #pragma unroll
    for (int ks = 0; ks < 64; ks += 32) {
        s16x8 af[2], bfr[3];
        #pragma unroll
        for (int mt = 0; mt < 2; ++mt)
            af[mt] = *(const s16x8*)(Qs + (moff + mt * 16 + col) * 64 + ks + kb);
        #pragma unroll
        for (int nt = 0; nt < 3; ++nt)
            bfr[nt] = *(const s16x8*)(Ats + (nt * 16 + col) * 64 + ks + kb);
        #pragma unroll
        for (int mt = 0; mt < 2; ++mt)
            #pragma unroll
            for (int nt = 0; nt < 3; ++nt)
                acc[mt][nt] = __builtin_amdgcn_mfma_f32_16x16x32_bf16(
                    af[mt], bfr[nt], acc[mt][nt], 0, 0, 0);
    }
    const int rbase = (lane >> 4) * 4;
    #pragma unroll
    for (int mt = 0; mt < 2; ++mt) {
        #pragma unroll
        for (int nt = 0; nt < 3; ++nt) {
            const int d = nt * 16 + col;
            #pragma unroll
            for (int r = 0; r < 4; ++r) {
                const int n = m0 + moff + mt * 16 + rbase + r;
                y[((size_t)b * 8192 + h2g * 1024 + (n >> 3)) * 384 + (n & 7) * 48 + d] =
                    __float2bfloat16(acc[mt][nt][r]);
            }
        }
    }
}

// ---------------------------------------------------------------------------
extern "C" void kernel_launch(void* const* d_in, const int* in_sizes, int n_in,
                              void* d_out, int out_size, void* d_ws, size_t ws_size,
                              hipStream_t stream)
{
    (void)in_sizes; (void)n_in; (void)out_size; (void)ws_size;
    const float* x      = (const float*)d_in[0];
    const float* cpe0_w = (const float*)d_in[2];
    const float* cpe0_b = (const float*)d_in[3];
    const float* cpe1_w = (const float*)d_in[4];
    const float* cpe1_b = (const float*)d_in[5];
    const float* n1g    = (const float*)d_in[6];
    const float* n1b    = (const float*)d_in[7];
    const float* q_w    = (const float*)d_in[8];
    const float* kv_w   = (const float*)d_in[9];
    const float* proj_w = (const float*)d_in[10];
    const float* proj_b = (const float*)d_in[11];
    const float* n2g    = (const float*)d_in[12];
    const float* n2b    = (const float*)d_in[13];
    const float* w1     = (const float*)d_in[14];
    const float* b1     = (const float*)d_in[15];
    const float* w2     = (const float*)d_in[16];
    const float* b2     = (const float*)d_in[17];

    char* ws = (char*)d_ws;
    // persistent weights: 0 .. 3.3 MiB
    bf16*  qkvT = (bf16*)(ws + 0);           // [896][384]
    bf16*  pwT  = (bf16*)(ws + 688128);      // [384][384]
    bf16*  w1T  = (bf16*)(ws + 983040);      // [1536][384]
    bf16*  w2T  = (bf16*)(ws + 2162688);     // [384][1536]
    float* wt0  = (float*)(ws + 3342336);
    float* wt1  = (float*)(ws + 3383808);
    // dynamic buffers
    bf16*  xf   = (bf16*)(ws + 4194304);     // 24 MiB residual1
    bf16*  qkv  = (bf16*)(ws + 29360128);    // 56 MiB [32768][896]
    float* attp = (float*)(ws + 88080384);   //  9 MiB
    bf16*  att  = (bf16*)(ws + 97517568);    //  144 KiB
    bf16*  yb   = (bf16*)(ws + 98566144);    // 24 MiB
    bf16*  t    = (bf16*)(ws + 123731968);   // 24 MiB LN out
    bf16*  xf3  = (bf16*)(ws + 148897792);   // 24 MiB residual2
    bf16*  h1   = (bf16*)(ws + 4194304);     // 96 MiB (phase-2; aliases xf..yb, all dead)

    // 0. merged prep
    prep_kernel<<<dim3(6609), dim3(256), 0, stream>>>(
        q_w, kv_w, proj_w, w1, w2, cpe0_w, cpe1_w,
        qkvT, pwT, w1T, w2T, wt0, wt1);

    // 1. CPE0 + LN1: xf(bf16) = x + dwconv(x) + b ; t = LN(xf)
    cpe_ln_kernel<float><<<dim3(1024), dim3(384), 0, stream>>>(
        x, wt0, cpe0_b, n1g, n1b, xf, t);
    // 2. merged q+kv projection: qkv = t @ qkvT^T   (256-row tile, K=384)
    gemm256_kernel<<<dim3(128, 7), dim3(512), 0, stream>>>(
        t, 384, qkvT, 384, qkv, 896, nullptr, 384, 0);
    // 3/4. channel-attention scores + softmax
    attp_kernel<<<dim3(32, 32), dim3(64), 0, stream>>>(qkv, attp);
    attred_kernel<<<dim3(48, 32), dim3(64), 0, stream>>>(attp, att);
    // 5. y = q @ att^T with scrambled reshape
    y_kernel<<<dim3(64, 32), dim3(256), 0, stream>>>(qkv, att, yb);
    // 6. proj (in-place bf16 residual): xf = yb @ pw + pb + xf
    gemm128_kernel<<<dim3(256, 3), dim3(256), 0, stream>>>(
        yb, 384, pwT, 384, xf, 384, xf, proj_b, 384, 384, 4);
    // 7. CPE1 + LN2: xf3(bf16) = xf + dwconv(xf) + b ; t = LN(xf3)
    cpe_ln_kernel<bf16><<<dim3(1024), dim3(384), 0, stream>>>(
        xf, wt1, cpe1_b, n2g, n2b, xf3, t);
    // 8. MLP: h1 = gelu(t@W1+b1); out = h1@W2 + b2 + xf3 (fp32)  [K=384!]
    gemm256_kernel<<<dim3(128, 12), dim3(512), 0, stream>>>(
        t, 384, w1T, 384, h1, 1536, b1, 384, 1);
    gemm128_kernel<<<dim3(256, 3), dim3(256), 0, stream>>>(
        h1, 1536, w2T, 1536, d_out, 384, xf3, b2, 384, 1536, 2 | 4);
}